// Round 7
// baseline (170.361 us; speedup 1.0000x reference)
//
#include <hip/hip_runtime.h>
#include <hip/hip_cooperative_groups.h>
#include <cstddef>
#include <cstdint>

namespace cg = cooperative_groups;

#define SEQ 2048
#define DIM 1024
#define NH 16
#define HD 64
#define CK 64
#define NCK (SEQ / CK)     // 32 chunks
#define KVR 65             // KV^T rows incl. ksum row
#define KVRP 80            // padded to 5 MFMA tiles

typedef __attribute__((ext_vector_type(8))) short short8;            // 8 bf16
typedef __attribute__((ext_vector_type(8))) unsigned short ushort8;  // 8 raw bf16
typedef __attribute__((ext_vector_type(4))) float fx4;

__device__ __forceinline__ float phi_fn(float x) {
    return x > 0.f ? x + 1.f : __expf(x);   // elu(x)+1
}
__device__ __forceinline__ float bf2f(unsigned short u) {
    return __uint_as_float((unsigned int)u << 16);
}
__device__ __forceinline__ unsigned short f2bf(float f) {
    unsigned int u = __float_as_uint(f);
    unsigned int r = (u + 0x7FFFu + ((u >> 16) & 1u)) >> 16;   // RNE
    return (unsigned short)r;
}

// ---- swizzled LDS helpers: row stride 64 ushort (128 B); byte ^= (row&7)<<4 ----
__device__ __forceinline__ void lds_write16(unsigned short* base, int row, int col, short8 v) {
    int byte = row * 128 + col * 2; byte ^= (row & 7) << 4;
    *(short8*)((char*)base + byte) = v;
}
__device__ __forceinline__ void lds_write2(unsigned short* base, int row, int col, unsigned short v) {
    int byte = row * 128 + col * 2; byte ^= (row & 7) << 4;
    *(unsigned short*)((char*)base + byte) = v;
}
__device__ __forceinline__ short8 lds_read_frag(const unsigned short* base, int row, int kcol) {
    int byte = row * 128 + kcol * 2; byte ^= (row & 7) << 4;
    return *(const short8*)((const char*)base + byte);
}

template<int N> __device__ __forceinline__ void waitv() {
    if constexpr (N == 0)       asm volatile("s_waitcnt vmcnt(0)"  ::: "memory");
    else if constexpr (N == 4)  asm volatile("s_waitcnt vmcnt(4)"  ::: "memory");
    else if constexpr (N == 5)  asm volatile("s_waitcnt vmcnt(5)"  ::: "memory");
    else if constexpr (N == 6)  asm volatile("s_waitcnt vmcnt(6)"  ::: "memory");
    else if constexpr (N == 8)  asm volatile("s_waitcnt vmcnt(8)"  ::: "memory");
    else if constexpr (N == 10) asm volatile("s_waitcnt vmcnt(10)" ::: "memory");
    else if constexpr (N == 12) asm volatile("s_waitcnt vmcnt(12)" ::: "memory");
    else                        asm volatile("s_waitcnt vmcnt(0)"  ::: "memory");
}

// -------- fused prep: x->bf16, W_qkv^T->bf16, W_out^T->bf16 (one launch) --------
__global__ __launch_bounds__(256)
void prep_fused(const float* __restrict__ x, unsigned short* __restrict__ xb,
                const float* __restrict__ W1, unsigned short* __restrict__ WT1,
                const float* __restrict__ W2, unsigned short* __restrict__ WT2)
{
    __shared__ float t[32][33];
    int b = blockIdx.x;
    if (b < 2048) {                       // x -> bf16 : 2048*256*4 = 2M elements
        const int i = (b * 256 + threadIdx.x) * 4;
        float4 v = *(const float4*)&x[i];
        ushort4 o;
        o.x = f2bf(v.x); o.y = f2bf(v.y); o.z = f2bf(v.z); o.w = f2bf(v.w);
        *(ushort4*)&xb[i] = o;
        return;
    }
    b -= 2048;
    const float* W; unsigned short* WT; int N, kb, nb;
    if (b < 96 * 32) {
        W = W1; WT = WT1; N = 3 * DIM;
        nb = (b % 96) * 32; kb = (b / 96) * 32;
    } else {
        b -= 96 * 32;
        W = W2; WT = WT2; N = DIM;
        nb = (b % 32) * 32; kb = (b / 32) * 32;
    }
    const int c = threadIdx.x & 31, r0 = threadIdx.x >> 5;
    #pragma unroll
    for (int i = 0; i < 4; ++i) {
        const int r = r0 + i * 8;
        t[r][c] = W[(size_t)(kb + r) * N + nb + c];
    }
    __syncthreads();
    #pragma unroll
    for (int i = 0; i < 4; ++i) {
        const int r = r0 + i * 8;
        WT[(size_t)(nb + r) * DIM + kb + c] = f2bf(t[c][r]);
    }
}

// ============ SLOTS-slot, 1-barrier/K-step pipelined bf16 MFMA GEMM ============
// C(MxN) = A(MxK) @ BT(NxK)^T.  BM=128, BK=64, BN=WAVES_N*NFRAG*16.
// Prefetch distance SLOTS-1: stage at iter t targets slot (t+SLOTS-1)%SLOTS,
// freed by iter t-1's readers (lgkmcnt(0) before the single end barrier).
// Counted vmcnt keeps SLOTS-2 tiles in flight across the barrier (T4);
// setprio (T5); XOR-swizzle both-sides (T2); XCD swizzle (T1).
template<int WAVES_M, int WAVES_N, int NFRAG, int SLOTS, int OUT_BF16>
__global__ __launch_bounds__(WAVES_M * WAVES_N * 64)
void gemm_pipe(const unsigned short* __restrict__ A,
               const unsigned short* __restrict__ BT,
               void* __restrict__ Cout, int M, int N, int K)
{
    constexpr int BN      = WAVES_N * NFRAG * 16;
    constexpr int THREADS = WAVES_M * WAVES_N * 64;
    constexpr int CHUNK   = THREADS * 16;              // bytes per load-op
    constexpr int ALOADS  = (128 * 64 * 2) / CHUNK;
    constexpr int BLOADS  = (BN * 64 * 2) / CHUNK;
    constexpr int LOADS   = ALOADS + BLOADS;

    __shared__ unsigned short As[SLOTS][128 * 64];
    __shared__ unsigned short Bs[SLOTS][BN * 64];

    const int tid = threadIdx.x, lane = tid & 63, wave = tid >> 6;
    const int wm = (wave / WAVES_N) * 64;
    const int wn = (wave % WAVES_N) * (NFRAG * 16);

    // XCD-aware block swizzle (nwg divisible by 8)
    int wg = blockIdx.y * gridDim.x + blockIdx.x;
    const int cpx = (gridDim.x * gridDim.y) >> 3;
    wg = (wg & 7) * cpx + (wg >> 3);
    const int bx = wg / gridDim.y;
    const int by = wg % gridDim.y;

    const int m0 = by * 128, n0 = bx * BN;
    const unsigned short* Abase = A + (size_t)m0 * K;
    const unsigned short* Bbase = BT + (size_t)n0 * K;
    const int nt = K >> 6;
    const int fr = lane & 15, fk = (lane >> 4) * 8;

    fx4 acc[4][NFRAG] = {};

    auto STAGE = [&](int slot, int t) {
        const int k0 = t << 6;
        #pragma unroll
        for (int q = 0; q < ALOADS; ++q) {
            const int L = q * CHUNK + tid * 16;                 // linear dest byte
            const int row = L >> 7;
            const int srcb = L ^ ((row & 7) << 4);              // inverse swizzle
            const unsigned short* g = Abase + (size_t)row * K + k0 + ((srcb & 127) >> 1);
            __builtin_amdgcn_global_load_lds(
                (const __attribute__((address_space(1))) void*)g,
                (__attribute__((address_space(3))) void*)((char*)&As[slot][0] + q * CHUNK + wave * 1024),
                16, 0, 0);
        }
        #pragma unroll
        for (int q = 0; q < BLOADS; ++q) {
            const int L = q * CHUNK + tid * 16;
            const int row = L >> 7;
            const int srcb = L ^ ((row & 7) << 4);
            const unsigned short* g = Bbase + (size_t)row * K + k0 + ((srcb & 127) >> 1);
            __builtin_amdgcn_global_load_lds(
                (const __attribute__((address_space(1))) void*)g,
                (__attribute__((address_space(3))) void*)((char*)&Bs[slot][0] + q * CHUNK + wave * 1024),
                16, 0, 0);
        }
    };

    // prologue: SLOTS-1 tiles in flight, wait for tile 0
    STAGE(0, 0); STAGE(1, 1);
    if constexpr (SLOTS == 4) STAGE(2, 2);
    waitv<(SLOTS - 2) * LOADS>();
    __builtin_amdgcn_s_barrier();

    for (int t = 0; t < nt; ++t) {
        const int cur = (SLOTS == 4) ? (t & 3) : (t % 3);
        short8 a0[4], a1[4], b0[NFRAG], b1[NFRAG];
        #pragma unroll
        for (int i = 0; i < 4; ++i) {
            a0[i] = lds_read_frag(&As[cur][0], wm + i * 16 + fr, fk);
            a1[i] = lds_read_frag(&As[cur][0], wm + i * 16 + fr, 32 + fk);
        }
        #pragma unroll
        for (int j = 0; j < NFRAG; ++j) {
            b0[j] = lds_read_frag(&Bs[cur][0], wn + j * 16 + fr, fk);
            b1[j] = lds_read_frag(&Bs[cur][0], wn + j * 16 + fr, 32 + fk);
        }

        const bool pf = (t + SLOTS - 1 < nt);
        if (pf) {
            const int ns = (SLOTS == 4) ? ((t + 3) & 3) : ((t + 2) % 3);
            STAGE(ns, t + SLOTS - 1);      // slot freed by iter t-1's readers
        }

        asm volatile("s_waitcnt lgkmcnt(0)" ::: "memory");
        __builtin_amdgcn_sched_barrier(0);   // rule #18: pin MFMA below the wait

        __builtin_amdgcn_s_setprio(1);
        #pragma unroll
        for (int i = 0; i < 4; ++i)
            #pragma unroll
            for (int j = 0; j < NFRAG; ++j)
                acc[i][j] = __builtin_amdgcn_mfma_f32_16x16x32_bf16(a0[i], b0[j], acc[i][j], 0, 0, 0);
        #pragma unroll
        for (int i = 0; i < 4; ++i)
            #pragma unroll
            for (int j = 0; j < NFRAG; ++j)
                acc[i][j] = __builtin_amdgcn_mfma_f32_16x16x32_bf16(a1[i], b1[j], acc[i][j], 0, 0, 0);
        __builtin_amdgcn_s_setprio(0);

        // guarantee tile t+1 landed; keep later tiles in flight across barrier
        if constexpr (SLOTS == 4) {
            if (t + 3 < nt)      waitv<2 * LOADS>();
            else if (t + 2 < nt) waitv<LOADS>();
            else                 waitv<0>();
        } else {
            if (t + 2 < nt)      waitv<LOADS>();
            else                 waitv<0>();
        }
        __builtin_amdgcn_s_barrier();
    }

    // C/D layout: col = lane&15, row = (lane>>4)*4 + reg
    const int cr = (lane >> 4) * 4, cc = lane & 15;
    #pragma unroll
    for (int i = 0; i < 4; ++i)
        #pragma unroll
        for (int j = 0; j < NFRAG; ++j) {
            const int m = m0 + wm + i * 16 + cr;
            const int n = n0 + wn + j * 16 + cc;
            #pragma unroll
            for (int r = 0; r < 4; ++r) {
                const float v = acc[i][j][r];
                if (OUT_BF16)
                    ((unsigned short*)Cout)[(size_t)(m + r) * N + n] = f2bf(v);
                else
                    ((float*)Cout)[(size_t)(m + r) * N + n] = v;
            }
        }
}

// ======== fused attention: chunk KV sums -> scan -> chunk outputs (cooperative) ========
// 512 blocks x 256 threads; block = (c = blk&31, h = blk>>5). Phase A's V^T LDS tile
// (incl. ones row + zero pad) is kept across grid.sync() and reused in phase C.
__global__ __launch_bounds__(256)
void attn_fused(const unsigned short* __restrict__ qkv, float* __restrict__ kvs,
                unsigned short* __restrict__ kvpb, unsigned short* __restrict__ attnb)
{
    cg::grid_group grid = cg::this_grid();
    __shared__ unsigned short pool[22528];   // 44 KB
    unsigned short* q_s = pool;              // [64][64] phi_q  (phase C) / kT (phase A)
    unsigned short* k_s = pool + 4096;       // [64][64] phi_k  (phase C)
    unsigned short* p_s = pool + 8192;       // [64][64] masked P (phase C)
    unsigned short* vT  = pool + 12288;      // [KVRP][64] V^T, row64=ones (A + C)
    unsigned short* kvp = pool + 17408;      // [KVRP][64] KVp^T_aug (phase C)

    const int blk = blockIdx.x;
    const int c = blk & 31, h = blk >> 5;
    const int tid = threadIdx.x, lane = tid & 63, wave = tid >> 6;
    const int s0 = c * CK;

    // ---------------- Phase A: chunk KV^T sums via MFMA ----------------
    unsigned short* kT = q_s;   // [i=d][s]
    #pragma unroll
    for (int part = 0; part < 2; ++part) {
        const int s = (tid >> 3) + part * 32;
        const int d0 = (tid & 7) * 8;
        const size_t base = (size_t)(s0 + s) * (3 * DIM) + (size_t)h * HD + d0;
        ushort8 kk = *(const ushort8*)&qkv[base + DIM];
        ushort8 vv = *(const ushort8*)&qkv[base + 2 * DIM];
        #pragma unroll
        for (int u = 0; u < 8; ++u) {
            lds_write2(kT, d0 + u, s, f2bf(phi_fn(bf2f(kk[u]))));
            lds_write2(vT, d0 + u, s, vv[u]);
        }
    }
    if (tid < 64) lds_write2(vT, 64, tid, 0x3F80);   // bf16 1.0
    for (int idx = tid; idx < 15 * 64; idx += 256)
        lds_write2(vT, 65 + (idx >> 6), idx & 63, 0);
    __syncthreads();

    {
        fx4 acc[5] = {};
        #pragma unroll
        for (int ks = 0; ks < 2; ++ks) {
            short8 b = lds_read_frag(kT, wave * 16 + (lane & 15), ks * 32 + (lane >> 4) * 8);
            #pragma unroll
            for (int mt = 0; mt < 5; ++mt) {
                short8 a = lds_read_frag(vT, mt * 16 + (lane & 15), ks * 32 + (lane >> 4) * 8);
                acc[mt] = __builtin_amdgcn_mfma_f32_16x16x32_bf16(a, b, acc[mt], 0, 0, 0);
            }
        }
        float* dst = kvs + (size_t)(h * NCK + c) * KVR * 64;
        const int i = wave * 16 + (lane & 15);
        #pragma unroll
        for (int mt = 0; mt < 5; ++mt)
            #pragma unroll
            for (int t = 0; t < 4; ++t) {
                const int j = mt * 16 + (lane >> 4) * 4 + t;
                if (j < KVR) dst[(size_t)j * 64 + i] = acc[mt][t];
            }
    }
    grid.sync();

    // ---------------- Phase B: exclusive prefix scan across chunks ----------------
    {
        const int e = blk * 256 + tid;
        if (e < NH * KVR * 64) {
            const int hh = e / (KVR * 64), off = e % (KVR * 64);
            const float* src = kvs + (size_t)hh * NCK * KVR * 64 + off;
            unsigned short* dst = kvpb + (size_t)hh * NCK * KVR * 64 + off;
            float v[NCK];
            #pragma unroll
            for (int c2 = 0; c2 < NCK; ++c2) v[c2] = src[(size_t)c2 * KVR * 64];
            float run = 0.f;
            #pragma unroll
            for (int c2 = 0; c2 < NCK; ++c2) {
                dst[(size_t)c2 * KVR * 64] = f2bf(run);
                run += v[c2];
            }
        }
    }
    grid.sync();

    // ---------------- Phase C: chunk outputs via MFMA (vT still live) ----------------
    #pragma unroll
    for (int part = 0; part < 2; ++part) {
        const int s = (tid >> 3) + part * 32;
        const int d0 = (tid & 7) * 8;
        const size_t base = (size_t)(s0 + s) * (3 * DIM) + (size_t)h * HD + d0;
        ushort8 qq = *(const ushort8*)&qkv[base];
        ushort8 kk = *(const ushort8*)&qkv[base + DIM];
        short8 qo, ko;
        #pragma unroll
        for (int u = 0; u < 8; ++u) {
            qo[u] = (short)f2bf(phi_fn(bf2f(qq[u])));
            ko[u] = (short)f2bf(phi_fn(bf2f(kk[u])));
        }
        lds_write16(q_s, s, d0, qo);
        lds_write16(k_s, s, d0, ko);
    }
    {
        const unsigned short* kv_src = kvpb + (size_t)(h * NCK + c) * KVR * 64;
        for (int idx = tid * 8; idx < KVR * 64; idx += 2048) {
            ushort8 kv8 = *(const ushort8*)&kv_src[idx];
            short8 kv8s;
            #pragma unroll
            for (int u = 0; u < 8; ++u) kv8s[u] = (short)kv8[u];
            lds_write16(kvp, idx >> 6, idx & 63, kv8s);
        }
        for (int idx = tid; idx < 15 * 64; idx += 256)
            lds_write2(kvp, 65 + (idx >> 6), idx & 63, 0);
    }
    __syncthreads();

    const int r0 = wave * 16;
    fx4 accp[4] = {};
    #pragma unroll
    for (int ks = 0; ks < 2; ++ks) {
        short8 aq = lds_read_frag(q_s, r0 + (lane & 15), ks * 32 + (lane >> 4) * 8);
        #pragma unroll
        for (int nt = 0; nt < 4; ++nt) {
            short8 bk = lds_read_frag(k_s, nt * 16 + (lane & 15), ks * 32 + (lane >> 4) * 8);
            accp[nt] = __builtin_amdgcn_mfma_f32_16x16x32_bf16(aq, bk, accp[nt], 0, 0, 0);
        }
    }
    #pragma unroll
    for (int nt = 0; nt < 4; ++nt)
        #pragma unroll
        for (int t = 0; t < 4; ++t) {
            const int r = r0 + (lane >> 4) * 4 + t, sc = nt * 16 + (lane & 15);
            lds_write2(p_s, r, sc, (sc <= r) ? f2bf(accp[nt][t]) : (unsigned short)0);
        }
    __syncthreads();

    fx4 acc[5] = {};
    #pragma unroll
    for (int ks = 0; ks < 2; ++ks) {
        short8 ap = lds_read_frag(p_s, r0 + (lane & 15), ks * 32 + (lane >> 4) * 8);
        short8 aq = lds_read_frag(q_s, r0 + (lane & 15), ks * 32 + (lane >> 4) * 8);
        #pragma unroll
        for (int nt = 0; nt < 5; ++nt) {
            short8 bv  = lds_read_frag(vT,  nt * 16 + (lane & 15), ks * 32 + (lane >> 4) * 8);
            short8 bkv = lds_read_frag(kvp, nt * 16 + (lane & 15), ks * 32 + (lane >> 4) * 8);
            acc[nt] = __builtin_amdgcn_mfma_f32_16x16x32_bf16(ap, bv,  acc[nt], 0, 0, 0);
            acc[nt] = __builtin_amdgcn_mfma_f32_16x16x32_bf16(aq, bkv, acc[nt], 0, 0, 0);
        }
    }
    float dinv[4];
    #pragma unroll
    for (int t = 0; t < 4; ++t) {
        const float d = __shfl(acc[4][t], lane & 48, 64);
        dinv[t] = 1.f / (d + 1e-6f);
    }
    #pragma unroll
    for (int nt = 0; nt < 4; ++nt)
        #pragma unroll
        for (int t = 0; t < 4; ++t) {
            const int r = r0 + (lane >> 4) * 4 + t, j = nt * 16 + (lane & 15);
            attnb[(size_t)(s0 + r) * DIM + (size_t)h * HD + j] = f2bf(acc[nt][t] * dinv[t]);
        }
}

extern "C" void kernel_launch(void* const* d_in, const int* in_sizes, int n_in,
                              void* d_out, int out_size, void* d_ws, size_t ws_size,
                              hipStream_t stream)
{
    const float* x     = (const float*)d_in[0];
    const float* W_qkv = (const float*)d_in[2];
    const float* W_out = (const float*)d_in[3];
    float* out = (float*)d_out;

    char* ws = (char*)d_ws;
    size_t off = 0;
    unsigned short* qkvb = (unsigned short*)(ws + off); off += (size_t)SEQ * 3 * DIM * 2;       // 12.6 MB
    unsigned short* xb   = (unsigned short*)(ws + off); off += (size_t)SEQ * DIM * 2;           //  4.2 MB
    float*          kvs  = (float*)         (ws + off); off += (size_t)NH * NCK * KVR * 64 * 4; //  8.5 MB
    unsigned short* kvpb = (unsigned short*)(ws + off); off += (size_t)NH * NCK * KVR * 64 * 2; //  4.3 MB
    unsigned short* wqt  = (unsigned short*)(ws + off); off += (size_t)3 * DIM * DIM * 2;       //  6.3 MB
    unsigned short* wot  = (unsigned short*)(ws + off); off += (size_t)DIM * DIM * 2;           //  2.1 MB
    unsigned short* attnb = xb;   // alias: qkv-GEMM finishes reading xb first (stream order)

    dim3 blk(256);

    prep_fused<<<dim3(2048 + 96 * 32 + 32 * 32), blk, 0, stream>>>(
        x, xb, W_qkv, wqt, W_out, wot);

    // qkv = x @ W_qkv : M=2048, N=3072, K=1024. BM=128,BN=192 -> 16x16=256 blocks,
    // 4-slot distance-3 pipeline, 160 KB LDS.
    gemm_pipe<2, 4, 3, 4, 1><<<dim3(3 * DIM / 192, SEQ / 128), dim3(512), 0, stream>>>(
        xb, wqt, qkvb, SEQ, 3 * DIM, DIM);

    // fused attention trio (cooperative): 512 blocks x 256 threads
    {
        void* args[] = {(void*)&qkvb, (void*)&kvs, (void*)&kvpb, (void*)&attnb};
        hipLaunchCooperativeKernel((const void*)attn_fused, dim3(NCK * NH), dim3(256),
                                   args, 0, stream);
    }

    // out = attn @ W_out : M=2048, N=1024, K=1024. BM=128,BN=64 -> 16x16=256 blocks
    gemm_pipe<2, 2, 2, 3, 0><<<dim3(DIM / 64, SEQ / 128), dim3(256), 0, stream>>>(
        attnb, wot, out, SEQ, DIM, DIM);
}

// Round 8
// 58.369 us; speedup vs baseline: 2.9187x; 2.9187x over previous
//
#include <hip/hip_runtime.h>
#include <cstddef>
#include <cstdint>

#define SEQ 2048
#define DIM 1024
#define NH 16
#define HD 64
#define CK 64
#define NCK (SEQ / CK)     // 32 chunks
#define KVR 65             // KV^T rows incl. ksum row
#define KVRP 80            // padded to 5 MFMA tiles

typedef __attribute__((ext_vector_type(8))) short short8;            // 8 bf16
typedef __attribute__((ext_vector_type(8))) unsigned short ushort8;  // 8 raw bf16
typedef __attribute__((ext_vector_type(4))) float fx4;

__device__ __forceinline__ float phi_fn(float x) {
    return x > 0.f ? x + 1.f : __expf(x);   // elu(x)+1
}
__device__ __forceinline__ float bf2f(unsigned short u) {
    return __uint_as_float((unsigned int)u << 16);
}
__device__ __forceinline__ unsigned short f2bf(float f) {
    unsigned int u = __float_as_uint(f);
    unsigned int r = (u + 0x7FFFu + ((u >> 16) & 1u)) >> 16;   // RNE
    return (unsigned short)r;
}

// ---- GEMM swizzle (matched with global_load_lds pre-swizzled source) ----
__device__ __forceinline__ short8 lds_read_frag(const unsigned short* base, int row, int kcol) {
    int byte = row * 128 + kcol * 2; byte ^= (row & 7) << 4;
    return *(const short8*)((const char*)base + byte);
}

// ---- trio swizzle: byte ^= ((row&7)^((row>>3)&7))<<4 — kills the 16-way
// write conflict of transposed per-element staging (row&7 was lane-invariant;
// row>>3 carries lane&7). Reads stay 2-way (free). Used consistently on all
// trio arrays, write AND read sides.
__device__ __forceinline__ int swz_t(int row, int col) {
    int byte = row * 128 + col * 2;
    return byte ^ ((((row & 7) ^ ((row >> 3) & 7))) << 4);
}
__device__ __forceinline__ void lds_write16_t(unsigned short* base, int row, int col, short8 v) {
    *(short8*)((char*)base + swz_t(row, col)) = v;
}
__device__ __forceinline__ void lds_write2_t(unsigned short* base, int row, int col, unsigned short v) {
    *(unsigned short*)((char*)base + swz_t(row, col)) = v;
}
__device__ __forceinline__ short8 lds_read_frag_t(const unsigned short* base, int row, int kcol) {
    return *(const short8*)((const char*)base + swz_t(row, kcol));
}

template<int N> __device__ __forceinline__ void waitv() {
    if constexpr (N == 0)       asm volatile("s_waitcnt vmcnt(0)"  ::: "memory");
    else if constexpr (N == 4)  asm volatile("s_waitcnt vmcnt(4)"  ::: "memory");
    else if constexpr (N == 5)  asm volatile("s_waitcnt vmcnt(5)"  ::: "memory");
    else if constexpr (N == 6)  asm volatile("s_waitcnt vmcnt(6)"  ::: "memory");
    else if constexpr (N == 8)  asm volatile("s_waitcnt vmcnt(8)"  ::: "memory");
    else if constexpr (N == 10) asm volatile("s_waitcnt vmcnt(10)" ::: "memory");
    else if constexpr (N == 12) asm volatile("s_waitcnt vmcnt(12)" ::: "memory");
    else                        asm volatile("s_waitcnt vmcnt(0)"  ::: "memory");
}

// -------- fused prep: x->bf16, W_qkv^T->bf16, W_out^T->bf16 (one launch) --------
__global__ __launch_bounds__(256)
void prep_fused(const float* __restrict__ x, unsigned short* __restrict__ xb,
                const float* __restrict__ W1, unsigned short* __restrict__ WT1,
                const float* __restrict__ W2, unsigned short* __restrict__ WT2)
{
    __shared__ float t[32][33];
    int b = blockIdx.x;
    if (b < 2048) {                       // x -> bf16 : 2048*256*4 = 2M elements
        const int i = (b * 256 + threadIdx.x) * 4;
        float4 v = *(const float4*)&x[i];
        ushort4 o;
        o.x = f2bf(v.x); o.y = f2bf(v.y); o.z = f2bf(v.z); o.w = f2bf(v.w);
        *(ushort4*)&xb[i] = o;
        return;
    }
    b -= 2048;
    const float* W; unsigned short* WT; int N, kb, nb;
    if (b < 96 * 32) {
        W = W1; WT = WT1; N = 3 * DIM;
        nb = (b % 96) * 32; kb = (b / 96) * 32;
    } else {
        b -= 96 * 32;
        W = W2; WT = WT2; N = DIM;
        nb = (b % 32) * 32; kb = (b / 32) * 32;
    }
    const int c = threadIdx.x & 31, r0 = threadIdx.x >> 5;
    #pragma unroll
    for (int i = 0; i < 4; ++i) {
        const int r = r0 + i * 8;
        t[r][c] = W[(size_t)(kb + r) * N + nb + c];
    }
    __syncthreads();
    #pragma unroll
    for (int i = 0; i < 4; ++i) {
        const int r = r0 + i * 8;
        WT[(size_t)(nb + r) * DIM + kb + c] = f2bf(t[c][r]);
    }
}

// ============ 3-slot, 1-barrier/K-step pipelined bf16 MFMA GEMM ============
// C(MxN) = A(MxK) @ BT(NxK)^T.  BM=128, BK=64, BN=WAVES_N*NFRAG*16.
// Prefetch distance 2: stage at iter t targets slot (t+2)%3, freed by iter
// t-1's readers (lgkmcnt(0) before the single end barrier). Counted vmcnt
// keeps 1 tile in flight across the barrier (T4); setprio (T5); XOR-swizzle
// both-sides (T2); XCD swizzle (T1).
template<int WAVES_M, int WAVES_N, int NFRAG, int OUT_BF16>
__global__ __launch_bounds__(WAVES_M * WAVES_N * 64)
void gemm_pipe(const unsigned short* __restrict__ A,
               const unsigned short* __restrict__ BT,
               void* __restrict__ Cout, int M, int N, int K)
{
    constexpr int BN      = WAVES_N * NFRAG * 16;
    constexpr int THREADS = WAVES_M * WAVES_N * 64;
    constexpr int CHUNK   = THREADS * 16;              // bytes per load-op
    constexpr int ALOADS  = (128 * 64 * 2) / CHUNK;
    constexpr int BLOADS  = (BN * 64 * 2) / CHUNK;
    constexpr int LOADS   = ALOADS + BLOADS;

    __shared__ unsigned short As[3][128 * 64];
    __shared__ unsigned short Bs[3][BN * 64];

    const int tid = threadIdx.x, lane = tid & 63, wave = tid >> 6;
    const int wm = (wave / WAVES_N) * 64;
    const int wn = (wave % WAVES_N) * (NFRAG * 16);

    // XCD-aware block swizzle (nwg divisible by 8)
    int wg = blockIdx.y * gridDim.x + blockIdx.x;
    const int cpx = (gridDim.x * gridDim.y) >> 3;
    wg = (wg & 7) * cpx + (wg >> 3);
    const int bx = wg / gridDim.y;
    const int by = wg % gridDim.y;

    const int m0 = by * 128, n0 = bx * BN;
    const unsigned short* Abase = A + (size_t)m0 * K;
    const unsigned short* Bbase = BT + (size_t)n0 * K;
    const int nt = K >> 6;
    const int fr = lane & 15, fk = (lane >> 4) * 8;

    fx4 acc[4][NFRAG] = {};

    auto STAGE = [&](int slot, int t) {
        const int k0 = t << 6;
        #pragma unroll
        for (int q = 0; q < ALOADS; ++q) {
            const int L = q * CHUNK + tid * 16;                 // linear dest byte
            const int row = L >> 7;
            const int srcb = L ^ ((row & 7) << 4);              // inverse swizzle
            const unsigned short* g = Abase + (size_t)row * K + k0 + ((srcb & 127) >> 1);
            __builtin_amdgcn_global_load_lds(
                (const __attribute__((address_space(1))) void*)g,
                (__attribute__((address_space(3))) void*)((char*)&As[slot][0] + q * CHUNK + wave * 1024),
                16, 0, 0);
        }
        #pragma unroll
        for (int q = 0; q < BLOADS; ++q) {
            const int L = q * CHUNK + tid * 16;
            const int row = L >> 7;
            const int srcb = L ^ ((row & 7) << 4);
            const unsigned short* g = Bbase + (size_t)row * K + k0 + ((srcb & 127) >> 1);
            __builtin_amdgcn_global_load_lds(
                (const __attribute__((address_space(1))) void*)g,
                (__attribute__((address_space(3))) void*)((char*)&Bs[slot][0] + q * CHUNK + wave * 1024),
                16, 0, 0);
        }
    };

    // prologue: distance-2 pipeline, wait for tile 0 (leave tile 1 in flight)
    STAGE(0, 0); STAGE(1, 1);
    waitv<LOADS>();
    __builtin_amdgcn_s_barrier();

    for (int t = 0; t < nt; ++t) {
        const int cur = t % 3;
        short8 a0[4], a1[4], b0[NFRAG], b1[NFRAG];
        #pragma unroll
        for (int i = 0; i < 4; ++i) {
            a0[i] = lds_read_frag(&As[cur][0], wm + i * 16 + fr, fk);
            a1[i] = lds_read_frag(&As[cur][0], wm + i * 16 + fr, 32 + fk);
        }
        #pragma unroll
        for (int j = 0; j < NFRAG; ++j) {
            b0[j] = lds_read_frag(&Bs[cur][0], wn + j * 16 + fr, fk);
            b1[j] = lds_read_frag(&Bs[cur][0], wn + j * 16 + fr, 32 + fk);
        }

        const bool pf = (t + 2 < nt);
        if (pf) STAGE((t + 2) % 3, t + 2);   // slot freed by iter t-1's readers

        asm volatile("s_waitcnt lgkmcnt(0)" ::: "memory");
        __builtin_amdgcn_sched_barrier(0);   // rule #18: pin MFMA below the wait

        __builtin_amdgcn_s_setprio(1);
        #pragma unroll
        for (int i = 0; i < 4; ++i)
            #pragma unroll
            for (int j = 0; j < NFRAG; ++j)
                acc[i][j] = __builtin_amdgcn_mfma_f32_16x16x32_bf16(a0[i], b0[j], acc[i][j], 0, 0, 0);
        #pragma unroll
        for (int i = 0; i < 4; ++i)
            #pragma unroll
            for (int j = 0; j < NFRAG; ++j)
                acc[i][j] = __builtin_amdgcn_mfma_f32_16x16x32_bf16(a1[i], b1[j], acc[i][j], 0, 0, 0);
        __builtin_amdgcn_s_setprio(0);

        // tile t+1 landed; keep t+2 in flight across the barrier
        if (pf) waitv<LOADS>(); else waitv<0>();
        __builtin_amdgcn_s_barrier();
    }

    // C/D layout: col = lane&15, row = (lane>>4)*4 + reg
    const int cr = (lane >> 4) * 4, cc = lane & 15;
    #pragma unroll
    for (int i = 0; i < 4; ++i)
        #pragma unroll
        for (int j = 0; j < NFRAG; ++j) {
            const int m = m0 + wm + i * 16 + cr;
            const int n = n0 + wn + j * 16 + cc;
            #pragma unroll
            for (int r = 0; r < 4; ++r) {
                const float v = acc[i][j][r];
                if (OUT_BF16)
                    ((unsigned short*)Cout)[(size_t)(m + r) * N + n] = f2bf(v);
                else
                    ((float*)Cout)[(size_t)(m + r) * N + n] = v;
            }
        }
}

// ---------------- Phase A: per-(head,chunk) KV^T sums via MFMA ----------------
__global__ __launch_bounds__(256)
void chunk_kv(const unsigned short* __restrict__ qkv, float* __restrict__ kvs)
{
    const int c = blockIdx.x, h = blockIdx.y;
    __shared__ unsigned short kT[64 * 64];    // [i=d][s], trio-swizzled
    __shared__ unsigned short vT[KVRP * 64];  // [j][s], row64=ones, 65-79=0
    const int tid = threadIdx.x, lane = tid & 63, wave = tid >> 6;
    const int s0 = c * CK;

    #pragma unroll
    for (int part = 0; part < 2; ++part) {
        const int s = (tid >> 3) + part * 32;
        const int d0 = (tid & 7) * 8;
        const size_t base = (size_t)(s0 + s) * (3 * DIM) + (size_t)h * HD + d0;
        ushort8 kk = *(const ushort8*)&qkv[base + DIM];
        ushort8 vv = *(const ushort8*)&qkv[base + 2 * DIM];
        #pragma unroll
        for (int u = 0; u < 8; ++u) {
            lds_write2_t(kT, d0 + u, s, f2bf(phi_fn(bf2f(kk[u]))));
            lds_write2_t(vT, d0 + u, s, vv[u]);
        }
    }
    if (tid < 64) lds_write2_t(vT, 64, tid, 0x3F80);   // bf16 1.0
    for (int idx = tid; idx < 15 * 64; idx += 256)
        lds_write2_t(vT, 65 + (idx >> 6), idx & 63, 0);
    __syncthreads();

    fx4 acc[5] = {};
    #pragma unroll
    for (int ks = 0; ks < 2; ++ks) {
        short8 b = lds_read_frag_t(kT, wave * 16 + (lane & 15), ks * 32 + (lane >> 4) * 8);
        #pragma unroll
        for (int mt = 0; mt < 5; ++mt) {
            short8 a = lds_read_frag_t(vT, mt * 16 + (lane & 15), ks * 32 + (lane >> 4) * 8);
            acc[mt] = __builtin_amdgcn_mfma_f32_16x16x32_bf16(a, b, acc[mt], 0, 0, 0);
        }
    }
    float* dst = kvs + (size_t)(h * NCK + c) * KVR * 64;
    const int i = wave * 16 + (lane & 15);
    #pragma unroll
    for (int mt = 0; mt < 5; ++mt)
        #pragma unroll
        for (int t = 0; t < 4; ++t) {
            const int j = mt * 16 + (lane >> 4) * 4 + t;
            if (j < KVR) dst[(size_t)j * 64 + i] = acc[mt][t];
        }
}

// ---------------- Phase B: exclusive prefix scan (ILP loads), bf16 out -------
__global__ __launch_bounds__(256)
void scan_kv(const float* __restrict__ kvs, unsigned short* __restrict__ kvpb)
{
    const int e = blockIdx.x * 256 + threadIdx.x;
    if (e >= NH * KVR * 64) return;
    const int h = e / (KVR * 64), off = e % (KVR * 64);
    const float* src = kvs + (size_t)h * NCK * KVR * 64 + off;
    unsigned short* dst = kvpb + (size_t)h * NCK * KVR * 64 + off;
    float v[NCK];
    #pragma unroll
    for (int c2 = 0; c2 < NCK; ++c2) v[c2] = src[(size_t)c2 * KVR * 64];
    float run = 0.f;
    #pragma unroll
    for (int c2 = 0; c2 < NCK; ++c2) {
        dst[(size_t)c2 * KVR * 64] = f2bf(run);
        run += v[c2];
    }
}

// ---------------- Phase C: per-(head,chunk) outputs via MFMA ----------------
__global__ __launch_bounds__(256)
void attn_chunk(const unsigned short* __restrict__ qkv,
                const unsigned short* __restrict__ kvpb,
                unsigned short* __restrict__ attnb)
{
    const int c = blockIdx.x, h = blockIdx.y;
    __shared__ unsigned short q_s[64 * 64];   // phi_q [r][d]
    __shared__ unsigned short k_s[64 * 64];   // phi_k [s][d]
    __shared__ unsigned short p_s[64 * 64];   // masked P bf16 [r][s]
    __shared__ unsigned short vT[KVRP * 64];  // V^T [j][s], row64=ones
    __shared__ unsigned short kvp[KVRP * 64]; // KVp^T_aug [j][d], row64=ksp
    const int tid = threadIdx.x, lane = tid & 63, wave = tid >> 6;
    const int s0 = c * CK;

    #pragma unroll
    for (int part = 0; part < 2; ++part) {
        const int s = (tid >> 3) + part * 32;
        const int d0 = (tid & 7) * 8;
        const size_t base = (size_t)(s0 + s) * (3 * DIM) + (size_t)h * HD + d0;
        ushort8 qq = *(const ushort8*)&qkv[base];
        ushort8 kk = *(const ushort8*)&qkv[base + DIM];
        ushort8 vv = *(const ushort8*)&qkv[base + 2 * DIM];
        short8 qo, ko;
        #pragma unroll
        for (int u = 0; u < 8; ++u) {
            qo[u] = (short)f2bf(phi_fn(bf2f(qq[u])));
            ko[u] = (short)f2bf(phi_fn(bf2f(kk[u])));
        }
        lds_write16_t(q_s, s, d0, qo);
        lds_write16_t(k_s, s, d0, ko);
        #pragma unroll
        for (int u = 0; u < 8; ++u)
            lds_write2_t(vT, d0 + u, s, vv[u]);
    }
    {
        const unsigned short* kv_src = kvpb + (size_t)(h * NCK + c) * KVR * 64;
        for (int idx = tid * 8; idx < KVR * 64; idx += 2048) {
            ushort8 kv8 = *(const ushort8*)&kv_src[idx];
            short8 kv8s;
            #pragma unroll
            for (int u = 0; u < 8; ++u) kv8s[u] = (short)kv8[u];
            lds_write16_t(kvp, idx >> 6, idx & 63, kv8s);
        }
    }
    if (tid < 64) lds_write2_t(vT, 64, tid, 0x3F80);
    for (int idx = tid; idx < 15 * 64; idx += 256) {
        lds_write2_t(vT, 65 + (idx >> 6), idx & 63, 0);
        lds_write2_t(kvp, 65 + (idx >> 6), idx & 63, 0);
    }
    __syncthreads();

    const int r0 = wave * 16;
    fx4 accp[4] = {};
    #pragma unroll
    for (int ks = 0; ks < 2; ++ks) {
        short8 aq = lds_read_frag_t(q_s, r0 + (lane & 15), ks * 32 + (lane >> 4) * 8);
        #pragma unroll
        for (int nt = 0; nt < 4; ++nt) {
            short8 bk = lds_read_frag_t(k_s, nt * 16 + (lane & 15), ks * 32 + (lane >> 4) * 8);
            accp[nt] = __builtin_amdgcn_mfma_f32_16x16x32_bf16(aq, bk, accp[nt], 0, 0, 0);
        }
    }
    #pragma unroll
    for (int nt = 0; nt < 4; ++nt)
        #pragma unroll
        for (int t = 0; t < 4; ++t) {
            const int r = r0 + (lane >> 4) * 4 + t, sc = nt * 16 + (lane & 15);
            lds_write2_t(p_s, r, sc, (sc <= r) ? f2bf(accp[nt][t]) : (unsigned short)0);
        }
    __syncthreads();

    fx4 acc[5] = {};
    #pragma unroll
    for (int ks = 0; ks < 2; ++ks) {
        short8 ap = lds_read_frag_t(p_s, r0 + (lane & 15), ks * 32 + (lane >> 4) * 8);
        short8 aq = lds_read_frag_t(q_s, r0 + (lane & 15), ks * 32 + (lane >> 4) * 8);
        #pragma unroll
        for (int nt = 0; nt < 5; ++nt) {
            short8 bv  = lds_read_frag_t(vT,  nt * 16 + (lane & 15), ks * 32 + (lane >> 4) * 8);
            short8 bkv = lds_read_frag_t(kvp, nt * 16 + (lane & 15), ks * 32 + (lane >> 4) * 8);
            acc[nt] = __builtin_amdgcn_mfma_f32_16x16x32_bf16(ap, bv,  acc[nt], 0, 0, 0);
            acc[nt] = __builtin_amdgcn_mfma_f32_16x16x32_bf16(aq, bkv, acc[nt], 0, 0, 0);
        }
    }
    float dinv[4];
    #pragma unroll
    for (int t = 0; t < 4; ++t) {
        const float d = __shfl(acc[4][t], lane & 48, 64);
        dinv[t] = 1.f / (d + 1e-6f);
    }
    #pragma unroll
    for (int nt = 0; nt < 4; ++nt)
        #pragma unroll
        for (int t = 0; t < 4; ++t) {
            const int r = r0 + (lane >> 4) * 4 + t, j = nt * 16 + (lane & 15);
            attnb[(size_t)(s0 + r) * DIM + (size_t)h * HD + j] = f2bf(acc[nt][t] * dinv[t]);
        }
}

extern "C" void kernel_launch(void* const* d_in, const int* in_sizes, int n_in,
                              void* d_out, int out_size, void* d_ws, size_t ws_size,
                              hipStream_t stream)
{
    const float* x     = (const float*)d_in[0];
    const float* W_qkv = (const float*)d_in[2];
    const float* W_out = (const float*)d_in[3];
    float* out = (float*)d_out;

    char* ws = (char*)d_ws;
    size_t off = 0;
    unsigned short* qkvb = (unsigned short*)(ws + off); off += (size_t)SEQ * 3 * DIM * 2;       // 12.6 MB
    unsigned short* xb   = (unsigned short*)(ws + off); off += (size_t)SEQ * DIM * 2;           //  4.2 MB
    float*          kvs  = (float*)         (ws + off); off += (size_t)NH * NCK * KVR * 64 * 4; //  8.5 MB
    unsigned short* kvpb = (unsigned short*)(ws + off); off += (size_t)NH * NCK * KVR * 64 * 2; //  4.3 MB
    unsigned short* wqt  = (unsigned short*)(ws + off); off += (size_t)3 * DIM * DIM * 2;       //  6.3 MB
    unsigned short* wot  = (unsigned short*)(ws + off); off += (size_t)DIM * DIM * 2;           //  2.1 MB
    unsigned short* attnb = xb;   // alias: qkv-GEMM finishes reading xb first (stream order)

    dim3 blk(256);

    prep_fused<<<dim3(2048 + 96 * 32 + 32 * 32), blk, 0, stream>>>(
        x, xb, W_qkv, wqt, W_out, wot);

    // qkv = x @ W_qkv : M=2048, N=3072, K=1024. BM=128,BN=192 -> 16x16=256 blocks (1/CU)
    gemm_pipe<2, 4, 3, 1><<<dim3(3 * DIM / 192, SEQ / 128), dim3(512), 0, stream>>>(
        xb, wqt, qkvb, SEQ, 3 * DIM, DIM);

    chunk_kv<<<dim3(NCK, NH), blk, 0, stream>>>(qkvb, kvs);
    scan_kv<<<dim3((NH * KVR * 64 + 255) / 256), blk, 0, stream>>>(kvs, kvpb);
    attn_chunk<<<dim3(NCK, NH), blk, 0, stream>>>(qkvb, kvpb, attnb);

    // out = attn @ W_out : M=2048, N=1024, K=1024. BM=128,BN=64 -> 16x16=256 blocks
    gemm_pipe<2, 2, 2, 0><<<dim3(DIM / 64, SEQ / 128), dim3(256), 0, stream>>>(
        attnb, wot, out, SEQ, DIM, DIM);
}

// Round 9
// 58.202 us; speedup vs baseline: 2.9271x; 1.0029x over previous
//
#include <hip/hip_runtime.h>
#include <cstddef>
#include <cstdint>

#define SEQ 2048
#define DIM 1024
#define NH 16
#define HD 64
#define CK 64
#define NCK (SEQ / CK)     // 32 chunks
#define KVR 65             // KV^T rows incl. ksum row
#define KVRP 80            // padded to 5 MFMA tiles

typedef __attribute__((ext_vector_type(8))) short short8;            // 8 bf16
typedef __attribute__((ext_vector_type(8))) unsigned short ushort8;  // 8 raw bf16
typedef __attribute__((ext_vector_type(4))) float fx4;

__device__ __forceinline__ float phi_fn(float x) {
    return x > 0.f ? x + 1.f : __expf(x);   // elu(x)+1
}
__device__ __forceinline__ float bf2f(unsigned short u) {
    return __uint_as_float((unsigned int)u << 16);
}
__device__ __forceinline__ unsigned short f2bf(float f) {
    unsigned int u = __float_as_uint(f);
    unsigned int r = (u + 0x7FFFu + ((u >> 16) & 1u)) >> 16;   // RNE
    return (unsigned short)r;
}

// ---- GEMM swizzle (matched with global_load_lds pre-swizzled source) ----
__device__ __forceinline__ short8 lds_read_frag(const unsigned short* base, int row, int kcol) {
    int byte = row * 128 + kcol * 2; byte ^= (row & 7) << 4;
    return *(const short8*)((const char*)base + byte);
}

// ---- trio swizzle: byte ^= ((row&7)^((row>>3)&7))<<4 — kills the 16-way
// write conflict of transposed per-element staging (row&7 was lane-invariant;
// row>>3 carries lane&7). Reads stay 2-way (free).
__device__ __forceinline__ int swz_t(int row, int col) {
    int byte = row * 128 + col * 2;
    return byte ^ ((((row & 7) ^ ((row >> 3) & 7))) << 4);
}
__device__ __forceinline__ void lds_write16_t(unsigned short* base, int row, int col, short8 v) {
    *(short8*)((char*)base + swz_t(row, col)) = v;
}
__device__ __forceinline__ void lds_write2_t(unsigned short* base, int row, int col, unsigned short v) {
    *(unsigned short*)((char*)base + swz_t(row, col)) = v;
}
__device__ __forceinline__ short8 lds_read_frag_t(const unsigned short* base, int row, int kcol) {
    return *(const short8*)((const char*)base + swz_t(row, kcol));
}

template<int N> __device__ __forceinline__ void waitv() {
    if constexpr (N == 0)       asm volatile("s_waitcnt vmcnt(0)"  ::: "memory");
    else if constexpr (N == 4)  asm volatile("s_waitcnt vmcnt(4)"  ::: "memory");
    else if constexpr (N == 5)  asm volatile("s_waitcnt vmcnt(5)"  ::: "memory");
    else if constexpr (N == 6)  asm volatile("s_waitcnt vmcnt(6)"  ::: "memory");
    else if constexpr (N == 8)  asm volatile("s_waitcnt vmcnt(8)"  ::: "memory");
    else if constexpr (N == 10) asm volatile("s_waitcnt vmcnt(10)" ::: "memory");
    else if constexpr (N == 12) asm volatile("s_waitcnt vmcnt(12)" ::: "memory");
    else                        asm volatile("s_waitcnt vmcnt(0)"  ::: "memory");
}

// -------- fused prep: x->bf16, W_qkv^T->bf16, W_out^T->bf16 (one launch) --------
__global__ __launch_bounds__(256)
void prep_fused(const float* __restrict__ x, unsigned short* __restrict__ xb,
                const float* __restrict__ W1, unsigned short* __restrict__ WT1,
                const float* __restrict__ W2, unsigned short* __restrict__ WT2)
{
    __shared__ float t[32][33];
    int b = blockIdx.x;
    if (b < 2048) {                       // x -> bf16 : 2048*256*4 = 2M elements
        const int i = (b * 256 + threadIdx.x) * 4;
        float4 v = *(const float4*)&x[i];
        ushort4 o;
        o.x = f2bf(v.x); o.y = f2bf(v.y); o.z = f2bf(v.z); o.w = f2bf(v.w);
        *(ushort4*)&xb[i] = o;
        return;
    }
    b -= 2048;
    const float* W; unsigned short* WT; int N, kb, nb;
    if (b < 96 * 32) {
        W = W1; WT = WT1; N = 3 * DIM;
        nb = (b % 96) * 32; kb = (b / 96) * 32;
    } else {
        b -= 96 * 32;
        W = W2; WT = WT2; N = DIM;
        nb = (b % 32) * 32; kb = (b / 32) * 32;
    }
    const int c = threadIdx.x & 31, r0 = threadIdx.x >> 5;
    #pragma unroll
    for (int i = 0; i < 4; ++i) {
        const int r = r0 + i * 8;
        t[r][c] = W[(size_t)(kb + r) * N + nb + c];
    }
    __syncthreads();
    #pragma unroll
    for (int i = 0; i < 4; ++i) {
        const int r = r0 + i * 8;
        WT[(size_t)(nb + r) * DIM + kb + c] = f2bf(t[c][r]);
    }
}

// ============ 3-slot, 1-barrier/K-step pipelined bf16 MFMA GEMM ============
// C(MxN) = A(MxK) @ BT(NxK)^T.  BM=128, BK=64, BN=WAVES_N*NFRAG*16.
// Prefetch distance 2: stage at iter t targets slot (t+2)%3, freed by iter
// t-1's readers before the single end barrier. Counted vmcnt keeps 1 tile in
// flight across the barrier (T4); setprio (T5); XOR-swizzle both-sides (T2);
// XCD swizzle (T1). NO manual lgkmcnt / sched_barrier in the loop: ds_reads
// are compiler-visible, so the compiler emits fine-grained counted lgkmcnt
// and interleaves tail reads with the first MFMAs (m97 behavior; manual
// lgkmcnt(0)+sched_barrier(0) was the m141 order-pinning anti-pattern).
template<int WAVES_M, int WAVES_N, int NFRAG, int OUT_BF16>
__global__ __launch_bounds__(WAVES_M * WAVES_N * 64)
void gemm_pipe(const unsigned short* __restrict__ A,
               const unsigned short* __restrict__ BT,
               void* __restrict__ Cout, int M, int N, int K)
{
    constexpr int BN      = WAVES_N * NFRAG * 16;
    constexpr int THREADS = WAVES_M * WAVES_N * 64;
    constexpr int CHUNK   = THREADS * 16;              // bytes per load-op
    constexpr int ALOADS  = (128 * 64 * 2) / CHUNK;
    constexpr int BLOADS  = (BN * 64 * 2) / CHUNK;
    constexpr int LOADS   = ALOADS + BLOADS;

    __shared__ unsigned short As[3][128 * 64];
    __shared__ unsigned short Bs[3][BN * 64];

    const int tid = threadIdx.x, lane = tid & 63, wave = tid >> 6;
    const int wm = (wave / WAVES_N) * 64;
    const int wn = (wave % WAVES_N) * (NFRAG * 16);

    // XCD-aware block swizzle (nwg divisible by 8)
    int wg = blockIdx.y * gridDim.x + blockIdx.x;
    const int cpx = (gridDim.x * gridDim.y) >> 3;
    wg = (wg & 7) * cpx + (wg >> 3);
    const int bx = wg / gridDim.y;
    const int by = wg % gridDim.y;

    const int m0 = by * 128, n0 = bx * BN;
    const unsigned short* Abase = A + (size_t)m0 * K;
    const unsigned short* Bbase = BT + (size_t)n0 * K;
    const int nt = K >> 6;
    const int fr = lane & 15, fk = (lane >> 4) * 8;

    fx4 acc[4][NFRAG] = {};

    auto STAGE = [&](int slot, int t) {
        const int k0 = t << 6;
        #pragma unroll
        for (int q = 0; q < ALOADS; ++q) {
            const int L = q * CHUNK + tid * 16;                 // linear dest byte
            const int row = L >> 7;
            const int srcb = L ^ ((row & 7) << 4);              // inverse swizzle
            const unsigned short* g = Abase + (size_t)row * K + k0 + ((srcb & 127) >> 1);
            __builtin_amdgcn_global_load_lds(
                (const __attribute__((address_space(1))) void*)g,
                (__attribute__((address_space(3))) void*)((char*)&As[slot][0] + q * CHUNK + wave * 1024),
                16, 0, 0);
        }
        #pragma unroll
        for (int q = 0; q < BLOADS; ++q) {
            const int L = q * CHUNK + tid * 16;
            const int row = L >> 7;
            const int srcb = L ^ ((row & 7) << 4);
            const unsigned short* g = Bbase + (size_t)row * K + k0 + ((srcb & 127) >> 1);
            __builtin_amdgcn_global_load_lds(
                (const __attribute__((address_space(1))) void*)g,
                (__attribute__((address_space(3))) void*)((char*)&Bs[slot][0] + q * CHUNK + wave * 1024),
                16, 0, 0);
        }
    };

    // prologue: distance-2 pipeline, wait for tile 0 (leave tile 1 in flight)
    STAGE(0, 0); STAGE(1, 1);
    waitv<LOADS>();
    __builtin_amdgcn_s_barrier();

    for (int t = 0; t < nt; ++t) {
        const int cur = t % 3;
        short8 a0[4], a1[4], b0[NFRAG], b1[NFRAG];
        #pragma unroll
        for (int i = 0; i < 4; ++i) {
            a0[i] = lds_read_frag(&As[cur][0], wm + i * 16 + fr, fk);
            a1[i] = lds_read_frag(&As[cur][0], wm + i * 16 + fr, 32 + fk);
        }
        #pragma unroll
        for (int j = 0; j < NFRAG; ++j) {
            b0[j] = lds_read_frag(&Bs[cur][0], wn + j * 16 + fr, fk);
            b1[j] = lds_read_frag(&Bs[cur][0], wn + j * 16 + fr, 32 + fk);
        }

        const bool pf = (t + 2 < nt);
        if (pf) STAGE((t + 2) % 3, t + 2);   // slot freed by iter t-1's readers

        // (no manual lgkmcnt / sched_barrier — compiler emits counted lgkmcnt
        //  per MFMA dependency and interleaves reads with early MFMAs)
        __builtin_amdgcn_s_setprio(1);
        #pragma unroll
        for (int i = 0; i < 4; ++i)
            #pragma unroll
            for (int j = 0; j < NFRAG; ++j)
                acc[i][j] = __builtin_amdgcn_mfma_f32_16x16x32_bf16(a0[i], b0[j], acc[i][j], 0, 0, 0);
        #pragma unroll
        for (int i = 0; i < 4; ++i)
            #pragma unroll
            for (int j = 0; j < NFRAG; ++j)
                acc[i][j] = __builtin_amdgcn_mfma_f32_16x16x32_bf16(a1[i], b1[j], acc[i][j], 0, 0, 0);
        __builtin_amdgcn_s_setprio(0);

        // tile t+1 landed; keep t+2 in flight across the barrier
        if (pf) waitv<LOADS>(); else waitv<0>();
        __builtin_amdgcn_s_barrier();
    }

    // C/D layout: col = lane&15, row = (lane>>4)*4 + reg
    const int cr = (lane >> 4) * 4, cc = lane & 15;
    #pragma unroll
    for (int i = 0; i < 4; ++i)
        #pragma unroll
        for (int j = 0; j < NFRAG; ++j) {
            const int m = m0 + wm + i * 16 + cr;
            const int n = n0 + wn + j * 16 + cc;
            #pragma unroll
            for (int r = 0; r < 4; ++r) {
                const float v = acc[i][j][r];
                if (OUT_BF16)
                    ((unsigned short*)Cout)[(size_t)(m + r) * N + n] = f2bf(v);
                else
                    ((float*)Cout)[(size_t)(m + r) * N + n] = v;
            }
        }
}

// ---------------- Phase A: per-(head,chunk) KV^T sums via MFMA ----------------
__global__ __launch_bounds__(256)
void chunk_kv(const unsigned short* __restrict__ qkv, float* __restrict__ kvs)
{
    const int c = blockIdx.x, h = blockIdx.y;
    __shared__ unsigned short kT[64 * 64];    // [i=d][s], trio-swizzled
    __shared__ unsigned short vT[KVRP * 64];  // [j][s], row64=ones, 65-79=0
    const int tid = threadIdx.x, lane = tid & 63, wave = tid >> 6;
    const int s0 = c * CK;

    #pragma unroll
    for (int part = 0; part < 2; ++part) {
        const int s = (tid >> 3) + part * 32;
        const int d0 = (tid & 7) * 8;
        const size_t base = (size_t)(s0 + s) * (3 * DIM) + (size_t)h * HD + d0;
        ushort8 kk = *(const ushort8*)&qkv[base + DIM];
        ushort8 vv = *(const ushort8*)&qkv[base + 2 * DIM];
        #pragma unroll
        for (int u = 0; u < 8; ++u) {
            lds_write2_t(kT, d0 + u, s, f2bf(phi_fn(bf2f(kk[u]))));
            lds_write2_t(vT, d0 + u, s, vv[u]);
        }
    }
    if (tid < 64) lds_write2_t(vT, 64, tid, 0x3F80);   // bf16 1.0
    for (int idx = tid; idx < 15 * 64; idx += 256)
        lds_write2_t(vT, 65 + (idx >> 6), idx & 63, 0);
    __syncthreads();

    fx4 acc[5] = {};
    #pragma unroll
    for (int ks = 0; ks < 2; ++ks) {
        short8 b = lds_read_frag_t(kT, wave * 16 + (lane & 15), ks * 32 + (lane >> 4) * 8);
        #pragma unroll
        for (int mt = 0; mt < 5; ++mt) {
            short8 a = lds_read_frag_t(vT, mt * 16 + (lane & 15), ks * 32 + (lane >> 4) * 8);
            acc[mt] = __builtin_amdgcn_mfma_f32_16x16x32_bf16(a, b, acc[mt], 0, 0, 0);
        }
    }
    float* dst = kvs + (size_t)(h * NCK + c) * KVR * 64;
    const int i = wave * 16 + (lane & 15);
    #pragma unroll
    for (int mt = 0; mt < 5; ++mt)
        #pragma unroll
        for (int t = 0; t < 4; ++t) {
            const int j = mt * 16 + (lane >> 4) * 4 + t;
            if (j < KVR) dst[(size_t)j * 64 + i] = acc[mt][t];
        }
}

// ---------------- Phase B: exclusive prefix scan (ILP loads), bf16 out -------
__global__ __launch_bounds__(256)
void scan_kv(const float* __restrict__ kvs, unsigned short* __restrict__ kvpb)
{
    const int e = blockIdx.x * 256 + threadIdx.x;
    if (e >= NH * KVR * 64) return;
    const int h = e / (KVR * 64), off = e % (KVR * 64);
    const float* src = kvs + (size_t)h * NCK * KVR * 64 + off;
    unsigned short* dst = kvpb + (size_t)h * NCK * KVR * 64 + off;
    float v[NCK];
    #pragma unroll
    for (int c2 = 0; c2 < NCK; ++c2) v[c2] = src[(size_t)c2 * KVR * 64];
    float run = 0.f;
    #pragma unroll
    for (int c2 = 0; c2 < NCK; ++c2) {
        dst[(size_t)c2 * KVR * 64] = f2bf(run);
        run += v[c2];
    }
}

// ---------------- Phase C: per-(head,chunk) outputs via MFMA ----------------
__global__ __launch_bounds__(256)
void attn_chunk(const unsigned short* __restrict__ qkv,
                const unsigned short* __restrict__ kvpb,
                unsigned short* __restrict__ attnb)
{
    const int c = blockIdx.x, h = blockIdx.y;
    __shared__ unsigned short q_s[64 * 64];   // phi_q [r][d]
    __shared__ unsigned short k_s[64 * 64];   // phi_k [s][d]
    __shared__ unsigned short p_s[64 * 64];   // masked P bf16 [r][s]
    __shared__ unsigned short vT[KVRP * 64];  // V^T [j][s], row64=ones
    __shared__ unsigned short kvp[KVRP * 64]; // KVp^T_aug [j][d], row64=ksp
    const int tid = threadIdx.x, lane = tid & 63, wave = tid >> 6;
    const int s0 = c * CK;

    #pragma unroll
    for (int part = 0; part < 2; ++part) {
        const int s = (tid >> 3) + part * 32;
        const int d0 = (tid & 7) * 8;
        const size_t base = (size_t)(s0 + s) * (3 * DIM) + (size_t)h * HD + d0;
        ushort8 qq = *(const ushort8*)&qkv[base];
        ushort8 kk = *(const ushort8*)&qkv[base + DIM];
        ushort8 vv = *(const ushort8*)&qkv[base + 2 * DIM];
        short8 qo, ko;
        #pragma unroll
        for (int u = 0; u < 8; ++u) {
            qo[u] = (short)f2bf(phi_fn(bf2f(qq[u])));
            ko[u] = (short)f2bf(phi_fn(bf2f(kk[u])));
        }
        lds_write16_t(q_s, s, d0, qo);
        lds_write16_t(k_s, s, d0, ko);
        #pragma unroll
        for (int u = 0; u < 8; ++u)
            lds_write2_t(vT, d0 + u, s, vv[u]);
    }
    {
        const unsigned short* kv_src = kvpb + (size_t)(h * NCK + c) * KVR * 64;
        for (int idx = tid * 8; idx < KVR * 64; idx += 2048) {
            ushort8 kv8 = *(const ushort8*)&kv_src[idx];
            short8 kv8s;
            #pragma unroll
            for (int u = 0; u < 8; ++u) kv8s[u] = (short)kv8[u];
            lds_write16_t(kvp, idx >> 6, idx & 63, kv8s);
        }
    }
    if (tid < 64) lds_write2_t(vT, 64, tid, 0x3F80);
    for (int idx = tid; idx < 15 * 64; idx += 256) {
        lds_write2_t(vT, 65 + (idx >> 6), idx & 63, 0);
        lds_write2_t(kvp, 65 + (idx >> 6), idx & 63, 0);
    }
    __syncthreads();

    const int r0 = wave * 16;
    fx4 accp[4] = {};
    #pragma unroll
    for (int ks = 0; ks < 2; ++ks) {
        short8 aq = lds_read_frag_t(q_s, r0 + (lane & 15), ks * 32 + (lane >> 4) * 8);
        #pragma unroll
        for (int nt = 0; nt < 4; ++nt) {
            short8 bk = lds_read_frag_t(k_s, nt * 16 + (lane & 15), ks * 32 + (lane >> 4) * 8);
            accp[nt] = __builtin_amdgcn_mfma_f32_16x16x32_bf16(aq, bk, accp[nt], 0, 0, 0);
        }
    }
    #pragma unroll
    for (int nt = 0; nt < 4; ++nt)
        #pragma unroll
        for (int t = 0; t < 4; ++t) {
            const int r = r0 + (lane >> 4) * 4 + t, sc = nt * 16 + (lane & 15);
            lds_write2_t(p_s, r, sc, (sc <= r) ? f2bf(accp[nt][t]) : (unsigned short)0);
        }
    __syncthreads();

    fx4 acc[5] = {};
    #pragma unroll
    for (int ks = 0; ks < 2; ++ks) {
        short8 ap = lds_read_frag_t(p_s, r0 + (lane & 15), ks * 32 + (lane >> 4) * 8);
        short8 aq = lds_read_frag_t(q_s, r0 + (lane & 15), ks * 32 + (lane >> 4) * 8);
        #pragma unroll
        for (int nt = 0; nt < 5; ++nt) {
            short8 bv  = lds_read_frag_t(vT,  nt * 16 + (lane & 15), ks * 32 + (lane >> 4) * 8);
            short8 bkv = lds_read_frag_t(kvp, nt * 16 + (lane & 15), ks * 32 + (lane >> 4) * 8);
            acc[nt] = __builtin_amdgcn_mfma_f32_16x16x32_bf16(ap, bv,  acc[nt], 0, 0, 0);
            acc[nt] = __builtin_amdgcn_mfma_f32_16x16x32_bf16(aq, bkv, acc[nt], 0, 0, 0);
        }
    }
    float dinv[4];
    #pragma unroll
    for (int t = 0; t < 4; ++t) {
        const float d = __shfl(acc[4][t], lane & 48, 64);
        dinv[t] = 1.f / (d + 1e-6f);
    }
    #pragma unroll
    for (int nt = 0; nt < 4; ++nt)
        #pragma unroll
        for (int t = 0; t < 4; ++t) {
            const int r = r0 + (lane >> 4) * 4 + t, j = nt * 16 + (lane & 15);
            attnb[(size_t)(s0 + r) * DIM + (size_t)h * HD + j] = f2bf(acc[nt][t] * dinv[t]);
        }
}

extern "C" void kernel_launch(void* const* d_in, const int* in_sizes, int n_in,
                              void* d_out, int out_size, void* d_ws, size_t ws_size,
                              hipStream_t stream)
{
    const float* x     = (const float*)d_in[0];
    const float* W_qkv = (const float*)d_in[2];
    const float* W_out = (const float*)d_in[3];
    float* out = (float*)d_out;

    char* ws = (char*)d_ws;
    size_t off = 0;
    unsigned short* qkvb = (unsigned short*)(ws + off); off += (size_t)SEQ * 3 * DIM * 2;       // 12.6 MB
    unsigned short* xb   = (unsigned short*)(ws + off); off += (size_t)SEQ * DIM * 2;           //  4.2 MB
    float*          kvs  = (float*)         (ws + off); off += (size_t)NH * NCK * KVR * 64 * 4; //  8.5 MB
    unsigned short* kvpb = (unsigned short*)(ws + off); off += (size_t)NH * NCK * KVR * 64 * 2; //  4.3 MB
    unsigned short* wqt  = (unsigned short*)(ws + off); off += (size_t)3 * DIM * DIM * 2;       //  6.3 MB
    unsigned short* wot  = (unsigned short*)(ws + off); off += (size_t)DIM * DIM * 2;           //  2.1 MB
    unsigned short* attnb = xb;   // alias: qkv-GEMM finishes reading xb first (stream order)

    dim3 blk(256);

    prep_fused<<<dim3(2048 + 96 * 32 + 32 * 32), blk, 0, stream>>>(
        x, xb, W_qkv, wqt, W_out, wot);

    // qkv = x @ W_qkv : M=2048, N=3072, K=1024. BM=128,BN=192 -> 16x16=256 blocks (1/CU)
    gemm_pipe<2, 4, 3, 1><<<dim3(3 * DIM / 192, SEQ / 128), dim3(512), 0, stream>>>(
        xb, wqt, qkvb, SEQ, 3 * DIM, DIM);

    chunk_kv<<<dim3(NCK, NH), blk, 0, stream>>>(qkvb, kvs);
    scan_kv<<<dim3((NH * KVR * 64 + 255) / 256), blk, 0, stream>>>(kvs, kvpb);
    attn_chunk<<<dim3(NCK, NH), blk, 0, stream>>>(qkvb, kvpb, attnb);

    // out = attn @ W_out : M=2048, N=1024, K=1024. BM=128,BN=64 -> 16x16=256 blocks
    gemm_pipe<2, 2, 2, 0><<<dim3(DIM / 64, SEQ / 128), dim3(256), 0, stream>>>(
        attnb, wot, out, SEQ, DIM, DIM);
}